// Round 1
// baseline (7289.819 us; speedup 1.0000x reference)
//
#include <hip/hip_runtime.h>
#include <cmath>

#define B_   128
#define T_   100
#define IN_  512
#define H_   1024
#define E_   8
#define HH_  512
#define GIN_ 5
#define GH_  8
#define KC_  128
#define NCH_ 12   // (IN_+H_)/KC_
#define XCH_ 4    // IN_/KC_

__device__ __forceinline__ float sigf(float x) { return 1.0f / (1.0f + expf(-x)); }

// Inner GEMM chunk: 32 quads (128 k) for 3 gate rows, lane = batch.
__device__ __forceinline__ void gemm_chunk(const float4* row4,
    const float4* wr4, const float4* wz4, const float4* wn4,
    int lane, float& ar, float& az, float& an)
{
  #pragma unroll 4
  for (int q = 0; q < 32; ++q) {
    float4 xv = row4[(q & 24) | ((q ^ lane) & 7)];
    float4 wr = wr4[q], wz = wz4[q], wn = wn4[q];
    ar = fmaf(xv.x, wr.x, ar); ar = fmaf(xv.y, wr.y, ar);
    ar = fmaf(xv.z, wr.z, ar); ar = fmaf(xv.w, wr.w, ar);
    az = fmaf(xv.x, wz.x, az); az = fmaf(xv.y, wz.y, az);
    az = fmaf(xv.z, wz.z, az); az = fmaf(xv.w, wz.w, az);
    an = fmaf(xv.x, wn.x, an); an = fmaf(xv.y, wn.y, an);
    an = fmaf(xv.z, wn.z, an); an = fmaf(xv.w, wn.w, an);
  }
}

// One GRU timestep. Blocks 0..511: main GRU GEMM (block = (j-tile of 4) x (b-half)).
// Block 512: gating GRU step (2 tiny layers) + softmax at t==T-1.
__global__ __launch_bounds__(256, 2) void gru_step_kernel(
    const float* __restrict__ X,
    const float* __restrict__ wih, const float* __restrict__ whh,
    const float* __restrict__ bih, const float* __restrict__ bhh,
    const float* __restrict__ gwih0, const float* __restrict__ gwhh0,
    const float* __restrict__ gbih0, const float* __restrict__ gbhh0,
    const float* __restrict__ gwih1, const float* __restrict__ gwhh1,
    const float* __restrict__ gbih1, const float* __restrict__ gbhh1,
    float* __restrict__ gh0, float* __restrict__ gh1,
    float* __restrict__ omega,
    const float* __restrict__ hprev, float* __restrict__ hnext,
    int t)
{
  __shared__ float4 lds4[64 * 32];   // 32 KB, swizzled [b][quad]

  if (blockIdx.x >= 512) {
    // ---- gating block: one thread per batch ----
    int b = threadIdx.x;
    if (b < B_) {
      float h0r[GH_], h1r[GH_];
      #pragma unroll
      for (int u = 0; u < GH_; ++u) { h0r[u] = gh0[b*GH_+u]; h1r[u] = gh1[b*GH_+u]; }
      float xt[GIN_];
      #pragma unroll
      for (int i = 0; i < GIN_; ++i)
        xt[i] = X[((size_t)b*T_ + t)*IN_ + (IN_ - GIN_) + i];

      float nh0[GH_];
      {
        float gi[3*GH_], gg[3*GH_];
        #pragma unroll
        for (int g = 0; g < 3*GH_; ++g) {
          float s = gbih0[g];
          #pragma unroll
          for (int i = 0; i < GIN_; ++i) s = fmaf(xt[i], gwih0[g*GIN_+i], s);
          gi[g] = s;
          float sh = gbhh0[g];
          #pragma unroll
          for (int u = 0; u < GH_; ++u) sh = fmaf(h0r[u], gwhh0[g*GH_+u], sh);
          gg[g] = sh;
        }
        #pragma unroll
        for (int u = 0; u < GH_; ++u) {
          float r = sigf(gi[u] + gg[u]);
          float z = sigf(gi[GH_+u] + gg[GH_+u]);
          float n = tanhf(gi[2*GH_+u] + r * gg[2*GH_+u]);
          nh0[u] = (1.f - z)*n + z*h0r[u];
        }
      }
      float nh1[GH_];
      {
        float gi[3*GH_], gg[3*GH_];
        #pragma unroll
        for (int g = 0; g < 3*GH_; ++g) {
          float s = gbih1[g];
          #pragma unroll
          for (int u = 0; u < GH_; ++u) s = fmaf(nh0[u], gwih1[g*GH_+u], s);
          gi[g] = s;
          float sh = gbhh1[g];
          #pragma unroll
          for (int u = 0; u < GH_; ++u) sh = fmaf(h1r[u], gwhh1[g*GH_+u], sh);
          gg[g] = sh;
        }
        #pragma unroll
        for (int u = 0; u < GH_; ++u) {
          float r = sigf(gi[u] + gg[u]);
          float z = sigf(gi[GH_+u] + gg[GH_+u]);
          float n = tanhf(gi[2*GH_+u] + r * gg[2*GH_+u]);
          nh1[u] = (1.f - z)*n + z*h1r[u];
        }
      }
      #pragma unroll
      for (int u = 0; u < GH_; ++u) { gh0[b*GH_+u] = nh0[u]; gh1[b*GH_+u] = nh1[u]; }

      if (t == T_ - 1) {
        float m = nh1[0];
        #pragma unroll
        for (int u = 1; u < GH_; ++u) m = fmaxf(m, nh1[u]);
        float ex[GH_]; float s = 0.f;
        #pragma unroll
        for (int u = 0; u < GH_; ++u) { ex[u] = expf(nh1[u] - m); s += ex[u]; }
        float inv = 1.f / s;
        #pragma unroll
        for (int u = 0; u < GH_; ++u) omega[b*GH_+u] = ex[u] * inv;
      }
    }
    return;
  }

  // ---- main GRU GEMM block ----
  const int tid  = threadIdx.x;
  const int bh   = blockIdx.x & 1;
  const int jt   = blockIdx.x >> 1;          // 0..255
  const int wv   = tid >> 6;                 // wave id 0..3
  const int lane = tid & 63;
  const int j    = __builtin_amdgcn_readfirstlane(jt * 4 + wv);
  const int b    = bh * 64 + lane;

  float ar = 0.f, az = 0.f, anx = 0.f, anh = 0.f;
  const float4* row4 = &lds4[lane * 32];

  for (int c = 0; c < NCH_; ++c) {
    __syncthreads();
    const int k0 = c * KC_;
    // stage 64 rows x 128 k into LDS (swizzled), coalesced float4 global loads
    #pragma unroll
    for (int it = 0; it < 8; ++it) {
      int f  = it * 256 + tid;               // 0..2047
      int bb = f >> 5, q = f & 31;
      const float* src;
      if (c < XCH_) src = X + ((size_t)(bh*64 + bb)*T_ + t)*IN_ + k0 + q*4;
      else          src = hprev + (size_t)(bh*64 + bb)*H_ + (k0 - IN_) + q*4;
      float4 v = *(const float4*)src;
      lds4[bb * 32 + ((q & 24) | ((q ^ bb) & 7))] = v;
    }
    __syncthreads();
    if (c < XCH_) {
      gemm_chunk(row4,
        (const float4*)(wih + (size_t)j*IN_        + k0),
        (const float4*)(wih + (size_t)(H_ + j)*IN_ + k0),
        (const float4*)(wih + (size_t)(2*H_ + j)*IN_ + k0),
        lane, ar, az, anx);
    } else {
      const int kk = k0 - IN_;
      gemm_chunk(row4,
        (const float4*)(whh + (size_t)j*H_        + kk),
        (const float4*)(whh + (size_t)(H_ + j)*H_ + kk),
        (const float4*)(whh + (size_t)(2*H_ + j)*H_ + kk),
        lane, ar, az, anh);
    }
  }

  float r = sigf(ar + bih[j]      + bhh[j]);
  float z = sigf(az + bih[H_+j]   + bhh[H_+j]);
  float n = tanhf(anx + bih[2*H_+j] + r * (anh + bhh[2*H_+j]));
  size_t hi = (size_t)b * H_ + j;
  float hp = hprev[hi];
  hnext[hi] = (1.f - z)*n + z*hp;
}

// MoE layer: out[b,j] = act( sum_e omega[b,e] * (dot(in[b,:],w[e,:,j]) + bias[e,j]) )
__global__ __launch_bounds__(256, 2) void moe_kernel(
    const float* __restrict__ in, const float* __restrict__ w,
    const float* __restrict__ bias, const float* __restrict__ omega,
    float* __restrict__ out, int K, int act)
{
  __shared__ float4 lin4[64 * 32];          // 32 KB, swizzled [b][quad]
  __shared__ float  ldsw[E_ * 4 * KC_];     // 16 KB, [e][jj][k]
  const int tid  = threadIdx.x;
  const int bh   = blockIdx.x & 1;
  const int jt   = blockIdx.x >> 1;         // 0..127
  const int wv   = tid >> 6;
  const int lane = tid & 63;
  const int j0   = jt * 4;
  const int j    = __builtin_amdgcn_readfirstlane(j0 + wv);
  const int b    = bh * 64 + lane;

  float acc[E_] = {0.f,0.f,0.f,0.f,0.f,0.f,0.f,0.f};
  const float4* row4 = &lin4[lane * 32];
  const int nch = K / KC_;

  for (int c = 0; c < nch; ++c) {
    __syncthreads();
    const int k0 = c * KC_;
    #pragma unroll
    for (int it = 0; it < 8; ++it) {
      int f = it * 256 + tid;
      int bb = f >> 5, q = f & 31;
      float4 v = *(const float4*)(in + (size_t)(bh*64 + bb)*K + k0 + q*4);
      lin4[bb * 32 + ((q & 24) | ((q ^ bb) & 7))] = v;
    }
    #pragma unroll
    for (int it = 0; it < 4; ++it) {
      int f = it * 256 + tid;                // 0..1023
      int e = f >> 7, k = f & 127;
      float4 v = *(const float4*)(w + ((size_t)e*K + k0 + k)*HH_ + j0);
      ldsw[(e*4 + 0)*KC_ + k] = v.x;
      ldsw[(e*4 + 1)*KC_ + k] = v.y;
      ldsw[(e*4 + 2)*KC_ + k] = v.z;
      ldsw[(e*4 + 3)*KC_ + k] = v.w;
    }
    __syncthreads();
    #pragma unroll 2
    for (int q = 0; q < 32; ++q) {
      float4 xv = row4[(q & 24) | ((q ^ lane) & 7)];
      #pragma unroll
      for (int e = 0; e < E_; ++e) {
        const float4 wq = *(const float4*)&ldsw[(e*4 + wv)*KC_ + 4*q];
        acc[e] = fmaf(xv.x, wq.x, acc[e]);
        acc[e] = fmaf(xv.y, wq.y, acc[e]);
        acc[e] = fmaf(xv.z, wq.z, acc[e]);
        acc[e] = fmaf(xv.w, wq.w, acc[e]);
      }
    }
  }

  float om[E_];
  #pragma unroll
  for (int e = 0; e < E_; ++e) om[e] = omega[b*E_ + e];
  float v = 0.f;
  #pragma unroll
  for (int e = 0; e < E_; ++e) v = fmaf(om[e], acc[e] + bias[e*HH_ + j], v);
  if (act == 0) v = (v > 0.f) ? v : expm1f(v);   // ELU
  else          v = fminf(fmaxf(v, 0.f), 1.f);   // clip [0,1]
  out[(size_t)b * HH_ + j] = v;
}

extern "C" void kernel_launch(void* const* d_in, const int* in_sizes, int n_in,
                              void* d_out, int out_size, void* d_ws, size_t ws_size,
                              hipStream_t stream) {
  (void)in_sizes; (void)n_in; (void)out_size; (void)ws_size;
  const float* X     = (const float*)d_in[0];
  const float* gwih0 = (const float*)d_in[1];
  const float* gwhh0 = (const float*)d_in[2];
  const float* gbih0 = (const float*)d_in[3];
  const float* gbhh0 = (const float*)d_in[4];
  const float* gwih1 = (const float*)d_in[5];
  const float* gwhh1 = (const float*)d_in[6];
  const float* gbih1 = (const float*)d_in[7];
  const float* gbhh1 = (const float*)d_in[8];
  const float* mwih  = (const float*)d_in[9];
  const float* mwhh  = (const float*)d_in[10];
  const float* mbih  = (const float*)d_in[11];
  const float* mbhh  = (const float*)d_in[12];
  const float* w1    = (const float*)d_in[13];
  const float* b1    = (const float*)d_in[14];
  const float* w2    = (const float*)d_in[15];
  const float* b2    = (const float*)d_in[16];
  const float* w3    = (const float*)d_in[17];
  const float* b3    = (const float*)d_in[18];

  float* ws = (float*)d_ws;
  float* h0 = ws;
  float* h1 = h0 + (size_t)B_ * H_;
  float* g0 = h1 + (size_t)B_ * H_;
  float* g1 = g0 + B_ * GH_;
  float* om = g1 + B_ * GH_;
  float* a1 = om + B_ * GH_;
  float* a2 = a1 + (size_t)B_ * HH_;

  // zero h ping-pong + gating state (one contiguous region at ws start)
  hipMemsetAsync(d_ws, 0, ((size_t)2*B_*H_ + 2*B_*GH_) * sizeof(float), stream);

  for (int t = 0; t < T_; ++t) {
    float* hp = (t & 1) ? h1 : h0;
    float* hn = (t & 1) ? h0 : h1;
    gru_step_kernel<<<513, 256, 0, stream>>>(X, mwih, mwhh, mbih, mbhh,
        gwih0, gwhh0, gbih0, gbhh0, gwih1, gwhh1, gbih1, gbhh1,
        g0, g1, om, hp, hn, t);
  }
  // final h is in h0 (t=99 writes h0)
  moe_kernel<<<256, 256, 0, stream>>>(h0, w1, b1, om, a1, H_, 0);
  moe_kernel<<<256, 256, 0, stream>>>(a1, w2, b2, om, a2, HH_, 0);
  moe_kernel<<<256, 256, 0, stream>>>(a2, w3, b3, om, (float*)d_out, HH_, 1);
}